// Round 1
// baseline (3735.395 us; speedup 1.0000x reference)
//
#include <hip/hip_runtime.h>
#include <hip/hip_cooperative_groups.h>

namespace cg = cooperative_groups;

#define BS 256
#define IN_LEN 512
#define T_OUT 64
#define H 1024
#define G4 4096
#define BK 64
#define NCH (H / BK)   // 16 K-chunks

typedef __attribute__((ext_vector_type(8))) short bf16x8;
typedef __attribute__((ext_vector_type(4))) float f32x4;

__device__ __forceinline__ unsigned short f2bf(float x) {
    union { float f; unsigned u; } v; v.f = x;
    unsigned r = v.u + 0x7fffu + ((v.u >> 16) & 1u);   // RTNE
    return (unsigned short)(r >> 16);
}
__device__ __forceinline__ float bf2f(unsigned short b) {
    union { unsigned u; float f; } v; v.u = ((unsigned)b) << 16;
    return v.f;
}
__device__ __forceinline__ float sigf(float x) { return 1.f / (1.f + __expf(-x)); }
__device__ __forceinline__ float tanhfast(float x) { return 1.f - 2.f / (__expf(2.f * x) + 1.f); }

__device__ __forceinline__ void gl_lds16(const void* g, void* l) {
    __builtin_amdgcn_global_load_lds((const __attribute__((address_space(1))) void*)g,
                                     (__attribute__((address_space(3))) void*)l, 16, 0, 0);
}

// swizzled LDS fragment read: tile is [64 rows][64 ushort], row = 128 B = 8 slots of 16 B;
// physical slot = logical slot ^ (row&7)  (matches the pre-swizzled global source below)
#define FRAG(base, row, ko) \
    (*(const bf16x8*)((const char*)(base) + ((((row) * 128 + (ko)) ^ ((((row) & 7)) << 4)))))

// ---- pack Wc = w_ih + w_hh AND w_hh alone into bf16 hi/lo, rows permuted p = hh*4+gate; split w_out
__global__ __launch_bounds__(256) void k_prep(const float4* __restrict__ w_ih4,
                                              const float4* __restrict__ w_hh4,
                                              const float4* __restrict__ w_out4,
                                              ushort4* __restrict__ Wch, ushort4* __restrict__ Wcl,
                                              ushort4* __restrict__ Whh, ushort4* __restrict__ Whl,
                                              ushort4* __restrict__ woh, ushort4* __restrict__ wol) {
    int row = blockIdx.x;        // source row 0..4095 (gate-major)
    int c4 = threadIdx.x;        // 0..255 float4 cols
    float4 a = w_ih4[row * 256 + c4];
    float4 b = w_hh4[row * 256 + c4];
    int p = ((row & 1023) << 2) | (row >> 10);   // packed row hh*4+gate
    float sx = a.x + b.x, sy = a.y + b.y, sz = a.z + b.z, sw = a.w + b.w;
    ushort4 hi, lo;
    hi.x = f2bf(sx); lo.x = f2bf(sx - bf2f(hi.x));
    hi.y = f2bf(sy); lo.y = f2bf(sy - bf2f(hi.y));
    hi.z = f2bf(sz); lo.z = f2bf(sz - bf2f(hi.z));
    hi.w = f2bf(sw); lo.w = f2bf(sw - bf2f(hi.w));
    Wch[p * 256 + c4] = hi;
    Wcl[p * 256 + c4] = lo;
    ushort4 h2, l2;
    h2.x = f2bf(b.x); l2.x = f2bf(b.x - bf2f(h2.x));
    h2.y = f2bf(b.y); l2.y = f2bf(b.y - bf2f(h2.y));
    h2.z = f2bf(b.z); l2.z = f2bf(b.z - bf2f(h2.z));
    h2.w = f2bf(b.w); l2.w = f2bf(b.w - bf2f(h2.w));
    Whh[p * 256 + c4] = h2;
    Whl[p * 256 + c4] = l2;
    if (row < 64) {
        float4 w = w_out4[row * 256 + c4];
        ushort4 h3, l3;
        h3.x = f2bf(w.x); l3.x = f2bf(w.x - bf2f(h3.x));
        h3.y = f2bf(w.y); l3.y = f2bf(w.y - bf2f(h3.y));
        h3.z = f2bf(w.z); l3.z = f2bf(w.z - bf2f(h3.z));
        h3.w = f2bf(w.w); l3.w = f2bf(w.w - bf2f(h3.w));
        woh[row * 256 + c4] = h3;
        wol[row * 256 + c4] = l3;
    }
}

// ---- g0p[p] = dot(start_token, w_ih[row]) + b_ih + b_hh (packed); bcp[p] = b_ih+b_hh
__global__ __launch_bounds__(256) void k_g0(const float4* __restrict__ st4,
                                            const float4* __restrict__ w_ih4,
                                            const float* __restrict__ b_ih,
                                            const float* __restrict__ b_hh,
                                            float* __restrict__ g0p, float* __restrict__ bcp) {
    int j = (blockIdx.x * 256 + threadIdx.x) >> 6;   // source row 0..4095
    int lane = threadIdx.x & 63;
    float s = 0.f;
#pragma unroll
    for (int q = 0; q < 4; ++q) {
        int idx = q * 64 + lane;
        float4 w4 = w_ih4[(size_t)j * 256 + idx];
        float4 s4 = st4[idx];
        s += w4.x * s4.x + w4.y * s4.y + w4.z * s4.z + w4.w * s4.w;
    }
#pragma unroll
    for (int off = 32; off > 0; off >>= 1) s += __shfl_down(s, off, 64);
    if (lane == 0) {
        int p = ((j & 1023) << 2) | (j >> 10);
        float bb = b_ih[j] + b_hh[j];
        bcp[p] = bb;
        g0p[p] = s + bb;
    }
}

// ---- h0 partial sums: split-K by 4 over input_len (1024 blocks -> ~full HBM BW on the 536 MB qf read)
__global__ __launch_bounds__(256) void k_h0_part(const float4* __restrict__ qf4,
                                                 const float* __restrict__ w_in,
                                                 float4* __restrict__ part) {
    int b = blockIdx.x >> 2;
    int kq = blockIdx.x & 3;
    int hq = threadIdx.x;
    const float4* p = qf4 + (size_t)b * IN_LEN * 256 + (size_t)kq * 128 * 256 + hq;
    const float* wv = w_in + kq * 128;
    float4 s = make_float4(0.f, 0.f, 0.f, 0.f);
#pragma unroll 8
    for (int i = 0; i < 128; ++i) {
        float w = wv[i];
        float4 q = p[(size_t)i * 256];
        s.x += q.x * w; s.y += q.y * w; s.z += q.z * w; s.w += q.w * w;
    }
    part[((size_t)kq * 256 + b) * 256 + hq] = s;
}

// ---- combine partials, add b_in, split to bf16 hi/lo
__global__ __launch_bounds__(256) void k_h0_comb(const float4* __restrict__ part,
                                                 const float* __restrict__ b_in,
                                                 ushort4* __restrict__ h0h, ushort4* __restrict__ h0l) {
    int idx = blockIdx.x * 256 + threadIdx.x;   // b*256 + hq
    float4 s = part[idx];
    float4 s1 = part[65536 + idx];
    float4 s2 = part[131072 + idx];
    float4 s3 = part[196608 + idx];
    s.x += s1.x + s2.x + s3.x;
    s.y += s1.y + s2.y + s3.y;
    s.z += s1.z + s2.z + s3.z;
    s.w += s1.w + s2.w + s3.w;
    float bi = b_in[0];
    s.x += bi; s.y += bi; s.z += bi; s.w += bi;
    ushort4 hi, lo;
    hi.x = f2bf(s.x); lo.x = f2bf(s.x - bf2f(hi.x));
    hi.y = f2bf(s.y); lo.y = f2bf(s.y - bf2f(hi.y));
    hi.z = f2bf(s.z); lo.z = f2bf(s.z - bf2f(hi.z));
    hi.w = f2bf(s.w); lo.w = f2bf(s.w - bf2f(hi.w));
    h0h[idx] = hi;
    h0l[idx] = lo;
}

// ---- persistent fused LSTM: 64 steps + probs GEMM, one cooperative launch.
// grid 256 (x = bid&63 -> 64 packed-col tile, y = bid>>6 -> 64 batch tile), 512 threads (8 waves).
// bid&63 keeps all 4 sharers of a weight tile on one XCD (64 % 8 == 0) -> weights L2-resident.
__global__ __launch_bounds__(512, 2) void k_lstm(const ushort* __restrict__ Wch, const ushort* __restrict__ Wcl,
                                                 const ushort* __restrict__ Whh, const ushort* __restrict__ Whl,
                                                 const float* __restrict__ g0p, const float* __restrict__ bcp,
                                                 const ushort* __restrict__ h0h, const ushort* __restrict__ h0l,
                                                 ushort* __restrict__ hsh, ushort* __restrict__ hsl,
                                                 const ushort* __restrict__ woh, const ushort* __restrict__ wol,
                                                 const float* __restrict__ b_out,
                                                 float* __restrict__ out_h, float* __restrict__ probs) {
    __shared__ __align__(16) ushort sA[2][2][64 * BK];   // [buf][hi/lo][64 rows x 64 k]
    __shared__ __align__(16) ushort sB[2][2][64 * BK];
    __shared__ __align__(16) float sC[64 * 68];

    cg::grid_group grid = cg::this_grid();

    const int tid = threadIdx.x;
    const int bid = blockIdx.x;
    const int n0 = (bid & 63) * 64;     // packed col base (hh0 = n0/4)
    const int m0 = (bid >> 6) * 64;     // batch base
    const int w = tid >> 6, l = tid & 63;
    const int wm = w & 1, wn = w >> 1;  // wave tile: 32 batch rows x 16 cols
    const int lm = l & 15, kg = l >> 4;

    // staging geometry: each wave stages 8 rows (1 KB) per tensor-half per chunk via one gl_lds16.
    // LDS dest is linear (wave base + lane*16); swizzle achieved by permuting the global SOURCE slot.
    const int srow = (w << 3) + (l >> 3);              // tile row this lane stages
    const int sl8 = ((l & 7) ^ ((l >> 3) & 7)) * 8;    // swizzled source slot (elements)
    const int ldsW = w * 512;                          // wave's LDS dest (ushort offset)

    const size_t obs = (size_t)(n0 + srow) * H + sl8;  // B per-lane source offset (elements)

    float creg0 = 0.f, creg1 = 0.f;                    // cell state lives in registers

    const int ra0 = wm * 32 + lm;
    const int rb = wn * 16 + lm;

#pragma unroll 1
    for (int t = 0; t < T_OUT; ++t) {
        const ushort* pBh = ((t == 0) ? Whh : Wch) + obs;
        const ushort* pBl = ((t == 0) ? Whl : Wcl) + obs;
        const ushort* pAh;
        const ushort* pAl;
        if (t == 0) {
            size_t oa = (size_t)(m0 + srow) * H + sl8;
            pAh = h0h + oa; pAl = h0l + oa;
        } else {
            size_t oa = ((size_t)(m0 + srow) * T_OUT + (t - 1)) * H + sl8;
            pAh = hsh + oa; pAl = hsl + oa;
        }
        const float* bias = (t == 0) ? g0p : bcp;

        f32x4 acc0 = (f32x4)(0.f), acc1 = (f32x4)(0.f);

        // prologue: stage chunk 0 -> buf 0
        gl_lds16(pAh, &sA[0][0][ldsW]);
        gl_lds16(pAl, &sA[0][1][ldsW]);
        gl_lds16(pBh, &sB[0][0][ldsW]);
        gl_lds16(pBh == pBl ? pBl : pBl, &sB[0][1][ldsW]);
        __syncthreads();

#pragma unroll 2
        for (int ch = 0; ch < NCH; ++ch) {
            const int cur = ch & 1;
            if (ch + 1 < NCH) {                        // issue next chunk BEFORE compute (2-phase)
                const int k0 = (ch + 1) * BK;
                gl_lds16(pAh + k0, &sA[cur ^ 1][0][ldsW]);
                gl_lds16(pAl + k0, &sA[cur ^ 1][1][ldsW]);
                gl_lds16(pBh + k0, &sB[cur ^ 1][0][ldsW]);
                gl_lds16(pBl + k0, &sB[cur ^ 1][1][ldsW]);
            }
            const ushort* Ah_ = sA[cur][0];
            const ushort* Al_ = sA[cur][1];
            const ushort* Bh_ = sB[cur][0];
            const ushort* Bl_ = sB[cur][1];
#pragma unroll
            for (int ks = 0; ks < 2; ++ks) {
                const int ko = ks * 64 + kg * 16;      // byte offset within row
                bf16x8 a0h = FRAG(Ah_, ra0, ko);
                bf16x8 a0l = FRAG(Al_, ra0, ko);
                bf16x8 a1h = FRAG(Ah_, ra0 + 16, ko);
                bf16x8 a1l = FRAG(Al_, ra0 + 16, ko);
                bf16x8 bh_ = FRAG(Bh_, rb, ko);
                bf16x8 bl_ = FRAG(Bl_, rb, ko);
                acc0 = __builtin_amdgcn_mfma_f32_16x16x32_bf16(a0h, bh_, acc0, 0, 0, 0);
                acc0 = __builtin_amdgcn_mfma_f32_16x16x32_bf16(a0h, bl_, acc0, 0, 0, 0);
                acc0 = __builtin_amdgcn_mfma_f32_16x16x32_bf16(a0l, bh_, acc0, 0, 0, 0);
                acc1 = __builtin_amdgcn_mfma_f32_16x16x32_bf16(a1h, bh_, acc1, 0, 0, 0);
                acc1 = __builtin_amdgcn_mfma_f32_16x16x32_bf16(a1h, bl_, acc1, 0, 0, 0);
                acc1 = __builtin_amdgcn_mfma_f32_16x16x32_bf16(a1l, bh_, acc1, 0, 0, 0);
            }
            __syncthreads();   // drains this chunk's prefetch; protects buf reuse
        }

        // spill C tile (rows = batch, cols = packed col)
        {
            const int c0 = wn * 16 + lm;
            const int r0 = wm * 32 + kg * 4;
#pragma unroll
            for (int r = 0; r < 4; ++r) sC[(r0 + r) * 68 + c0] = acc0[r];
#pragma unroll
            for (int r = 0; r < 4; ++r) sC[(r0 + 16 + r) * 68 + c0] = acc1[r];
        }
        __syncthreads();

        // cell update: 2 cells/thread, c stays in registers
#pragma unroll
        for (int q = 0; q < 2; ++q) {
            int cid = tid + q * 512;
            int bl_ = cid >> 4, hl = cid & 15;
            float4 gv = *(const float4*)&sC[bl_ * 68 + hl * 4];   // i,f,g,o
            float4 bv = *(const float4*)&bias[n0 + hl * 4];
            float cold = q ? creg1 : creg0;
            float ig = gv.x + bv.x, fg = gv.y + bv.y, gg = gv.z + bv.z, og = gv.w + bv.w;
            float cn = sigf(fg) * cold + sigf(ig) * tanhfast(gg);
            float hn = sigf(og) * tanhfast(cn);
            if (q) creg1 = cn; else creg0 = cn;
            int b = m0 + bl_;
            int hh = (n0 >> 2) + hl;
            size_t idx = ((size_t)b * T_OUT + t) * H + hh;
            out_h[idx] = hn;
            unsigned short hb = f2bf(hn);
            hsh[idx] = hb;
            hsl[idx] = f2bf(hn - bf2f(hb));
        }
        grid.sync();   // h_t visible to all XCDs; column t vs t-1 never alias -> no double buffer
    }

    // ---- probs = hs @ w_out^T + b_out; block bid covers hs rows [bid*64, bid*64+64) (= batch bid, all t)
    {
        size_t oa = ((size_t)(bid * 64 + srow)) * H + sl8;
        const ushort* pAh = hsh + oa;
        const ushort* pAl = hsl + oa;
        const ushort* pBh = woh + (size_t)srow * H + sl8;
        const ushort* pBl = wol + (size_t)srow * H + sl8;

        f32x4 acc0 = (f32x4)(0.f), acc1 = (f32x4)(0.f);

        gl_lds16(pAh, &sA[0][0][ldsW]);
        gl_lds16(pAl, &sA[0][1][ldsW]);
        gl_lds16(pBh, &sB[0][0][ldsW]);
        gl_lds16(pBl, &sB[0][1][ldsW]);
        __syncthreads();

#pragma unroll 2
        for (int ch = 0; ch < NCH; ++ch) {
            const int cur = ch & 1;
            if (ch + 1 < NCH) {
                const int k0 = (ch + 1) * BK;
                gl_lds16(pAh + k0, &sA[cur ^ 1][0][ldsW]);
                gl_lds16(pAl + k0, &sA[cur ^ 1][1][ldsW]);
                gl_lds16(pBh + k0, &sB[cur ^ 1][0][ldsW]);
                gl_lds16(pBl + k0, &sB[cur ^ 1][1][ldsW]);
            }
            const ushort* Ah_ = sA[cur][0];
            const ushort* Al_ = sA[cur][1];
            const ushort* Bh_ = sB[cur][0];
            const ushort* Bl_ = sB[cur][1];
#pragma unroll
            for (int ks = 0; ks < 2; ++ks) {
                const int ko = ks * 64 + kg * 16;
                bf16x8 a0h = FRAG(Ah_, ra0, ko);
                bf16x8 a0l = FRAG(Al_, ra0, ko);
                bf16x8 a1h = FRAG(Ah_, ra0 + 16, ko);
                bf16x8 a1l = FRAG(Al_, ra0 + 16, ko);
                bf16x8 bh_ = FRAG(Bh_, rb, ko);
                bf16x8 bl_ = FRAG(Bl_, rb, ko);
                acc0 = __builtin_amdgcn_mfma_f32_16x16x32_bf16(a0h, bh_, acc0, 0, 0, 0);
                acc0 = __builtin_amdgcn_mfma_f32_16x16x32_bf16(a0h, bl_, acc0, 0, 0, 0);
                acc0 = __builtin_amdgcn_mfma_f32_16x16x32_bf16(a0l, bh_, acc0, 0, 0, 0);
                acc1 = __builtin_amdgcn_mfma_f32_16x16x32_bf16(a1h, bh_, acc1, 0, 0, 0);
                acc1 = __builtin_amdgcn_mfma_f32_16x16x32_bf16(a1h, bl_, acc1, 0, 0, 0);
                acc1 = __builtin_amdgcn_mfma_f32_16x16x32_bf16(a1l, bh_, acc1, 0, 0, 0);
            }
            __syncthreads();
        }

        const int col = wn * 16 + lm;
        const float bo = b_out[col];
        const int rowb = bid * 64 + wm * 32 + kg * 4;
#pragma unroll
        for (int r = 0; r < 4; ++r)
            probs[(size_t)(rowb + r) * 64 + col] = acc0[r] + bo;
#pragma unroll
        for (int r = 0; r < 4; ++r)
            probs[(size_t)(rowb + 16 + r) * 64 + col] = acc1[r] + bo;
    }
}

extern "C" void kernel_launch(void* const* d_in, const int* in_sizes, int n_in,
                              void* d_out, int out_size, void* d_ws, size_t ws_size,
                              hipStream_t stream) {
    const float* qf    = (const float*)d_in[1];
    const float* st    = (const float*)d_in[4];
    const float* w_in  = (const float*)d_in[5];
    const float* b_in  = (const float*)d_in[6];
    const float* w_ih  = (const float*)d_in[7];
    const float* w_hh  = (const float*)d_in[8];
    const float* b_ih  = (const float*)d_in[9];
    const float* b_hh  = (const float*)d_in[10];
    const float* w_out = (const float*)d_in[11];
    const float* b_out = (const float*)d_in[12];

    float* probs = (float*)d_out;                        // [256][64][64]
    float* out_h = probs + (size_t)BS * T_OUT * 64;      // [256][64][1024]

    char* ws = (char*)d_ws;
    ushort* Wch   = (ushort*)ws; ws += (size_t)G4 * H * 2;        // 8 MB
    ushort* Wcl   = (ushort*)ws; ws += (size_t)G4 * H * 2;        // 8 MB
    ushort* Whh_h = (ushort*)ws; ws += (size_t)G4 * H * 2;        // 8 MB
    ushort* Whh_l = (ushort*)ws; ws += (size_t)G4 * H * 2;        // 8 MB
    ushort* woh   = (ushort*)ws; ws += (size_t)64 * H * 2;
    ushort* wol   = (ushort*)ws; ws += (size_t)64 * H * 2;
    float*  bcp   = (float*)ws;  ws += G4 * 4;
    float*  g0p   = (float*)ws;  ws += G4 * 4;
    ushort* h0h   = (ushort*)ws; ws += (size_t)BS * H * 2;        // 512 KB
    ushort* h0l   = (ushort*)ws; ws += (size_t)BS * H * 2;
    ushort* hsh   = (ushort*)ws; ws += (size_t)BS * T_OUT * H * 2; // 32 MB
    ushort* hsl   = (ushort*)ws; ws += (size_t)BS * T_OUT * H * 2; // 32 MB
    float*  part  = (float*)ws;  ws += (size_t)4 * 256 * 256 * 16; // 4 MB

    k_prep<<<G4, 256, 0, stream>>>((const float4*)w_ih, (const float4*)w_hh, (const float4*)w_out,
                                   (ushort4*)Wch, (ushort4*)Wcl, (ushort4*)Whh_h, (ushort4*)Whh_l,
                                   (ushort4*)woh, (ushort4*)wol);
    k_g0<<<G4 / 4, 256, 0, stream>>>((const float4*)st, (const float4*)w_ih, b_ih, b_hh, g0p, bcp);
    k_h0_part<<<BS * 4, 256, 0, stream>>>((const float4*)qf, w_in, (float4*)part);
    k_h0_comb<<<BS, 256, 0, stream>>>((const float4*)part, b_in, (ushort4*)h0h, (ushort4*)h0l);

    void* args[] = {(void*)&Wch, (void*)&Wcl, (void*)&Whh_h, (void*)&Whh_l,
                    (void*)&g0p, (void*)&bcp, (void*)&h0h, (void*)&h0l,
                    (void*)&hsh, (void*)&hsl, (void*)&woh, (void*)&wol,
                    (void*)&b_out, (void*)&out_h, (void*)&probs};
    hipLaunchCooperativeKernel(k_lstm, dim3(256), dim3(512), args, 0, stream);
}

// Round 2
// 1909.729 us; speedup vs baseline: 1.9560x; 1.9560x over previous
//
#include <hip/hip_runtime.h>

#define BS 256
#define IN_LEN 512
#define T_OUT 64
#define H 1024
#define G4 4096
#define BK 64
#define NCH (H / BK)   // 16 K-chunks

typedef __attribute__((ext_vector_type(8))) short bf16x8;
typedef __attribute__((ext_vector_type(4))) float f32x4;

__device__ __forceinline__ unsigned short f2bf(float x) {
    union { float f; unsigned u; } v; v.f = x;
    unsigned r = v.u + 0x7fffu + ((v.u >> 16) & 1u);   // RTNE
    return (unsigned short)(r >> 16);
}
__device__ __forceinline__ float bf2f(unsigned short b) {
    union { unsigned u; float f; } v; v.u = ((unsigned)b) << 16;
    return v.f;
}
__device__ __forceinline__ float sigf(float x) { return 1.f / (1.f + __expf(-x)); }
__device__ __forceinline__ float tanhfast(float x) { return 1.f - 2.f / (__expf(2.f * x) + 1.f); }

__device__ __forceinline__ void gl_lds16(const void* g, void* l) {
    __builtin_amdgcn_global_load_lds((const __attribute__((address_space(1))) void*)g,
                                     (__attribute__((address_space(3))) void*)l, 16, 0, 0);
}

// swizzled LDS fragment read: tile is [64 rows][64 ushort], row = 128 B = 8 slots of 16 B;
// physical slot = logical slot ^ (row&7)  (matches the pre-swizzled global source below)
#define FRAG(base, row, ko) \
    (*(const bf16x8*)((const char*)(base) + ((((row) * 128 + (ko)) ^ ((((row) & 7)) << 4)))))

// ---- pack Wc = w_ih + w_hh AND w_hh alone into bf16 hi/lo, rows permuted p = hh*4+gate; split w_out
__global__ __launch_bounds__(256) void k_prep(const float4* __restrict__ w_ih4,
                                              const float4* __restrict__ w_hh4,
                                              const float4* __restrict__ w_out4,
                                              ushort4* __restrict__ Wch, ushort4* __restrict__ Wcl,
                                              ushort4* __restrict__ Whh, ushort4* __restrict__ Whl,
                                              ushort4* __restrict__ woh, ushort4* __restrict__ wol) {
    int row = blockIdx.x;        // source row 0..4095 (gate-major)
    int c4 = threadIdx.x;        // 0..255 float4 cols
    float4 a = w_ih4[row * 256 + c4];
    float4 b = w_hh4[row * 256 + c4];
    int p = ((row & 1023) << 2) | (row >> 10);   // packed row hh*4+gate
    float sx = a.x + b.x, sy = a.y + b.y, sz = a.z + b.z, sw = a.w + b.w;
    ushort4 hi, lo;
    hi.x = f2bf(sx); lo.x = f2bf(sx - bf2f(hi.x));
    hi.y = f2bf(sy); lo.y = f2bf(sy - bf2f(hi.y));
    hi.z = f2bf(sz); lo.z = f2bf(sz - bf2f(hi.z));
    hi.w = f2bf(sw); lo.w = f2bf(sw - bf2f(hi.w));
    Wch[p * 256 + c4] = hi;
    Wcl[p * 256 + c4] = lo;
    ushort4 h2, l2;
    h2.x = f2bf(b.x); l2.x = f2bf(b.x - bf2f(h2.x));
    h2.y = f2bf(b.y); l2.y = f2bf(b.y - bf2f(h2.y));
    h2.z = f2bf(b.z); l2.z = f2bf(b.z - bf2f(h2.z));
    h2.w = f2bf(b.w); l2.w = f2bf(b.w - bf2f(h2.w));
    Whh[p * 256 + c4] = h2;
    Whl[p * 256 + c4] = l2;
    if (row < 64) {
        float4 w = w_out4[row * 256 + c4];
        ushort4 h3, l3;
        h3.x = f2bf(w.x); l3.x = f2bf(w.x - bf2f(h3.x));
        h3.y = f2bf(w.y); l3.y = f2bf(w.y - bf2f(h3.y));
        h3.z = f2bf(w.z); l3.z = f2bf(w.z - bf2f(h3.z));
        h3.w = f2bf(w.w); l3.w = f2bf(w.w - bf2f(h3.w));
        woh[row * 256 + c4] = h3;
        wol[row * 256 + c4] = l3;
    }
}

// ---- g0p[p] = dot(start_token, w_ih[row]) + b_ih + b_hh (packed); bcp[p] = b_ih+b_hh
__global__ __launch_bounds__(256) void k_g0(const float4* __restrict__ st4,
                                            const float4* __restrict__ w_ih4,
                                            const float* __restrict__ b_ih,
                                            const float* __restrict__ b_hh,
                                            float* __restrict__ g0p, float* __restrict__ bcp) {
    int j = (blockIdx.x * 256 + threadIdx.x) >> 6;   // source row 0..4095
    int lane = threadIdx.x & 63;
    float s = 0.f;
#pragma unroll
    for (int q = 0; q < 4; ++q) {
        int idx = q * 64 + lane;
        float4 w4 = w_ih4[(size_t)j * 256 + idx];
        float4 s4 = st4[idx];
        s += w4.x * s4.x + w4.y * s4.y + w4.z * s4.z + w4.w * s4.w;
    }
#pragma unroll
    for (int off = 32; off > 0; off >>= 1) s += __shfl_down(s, off, 64);
    if (lane == 0) {
        int p = ((j & 1023) << 2) | (j >> 10);
        float bb = b_ih[j] + b_hh[j];
        bcp[p] = bb;
        g0p[p] = s + bb;
    }
}

// ---- h0 partial sums: split-K by 4 over input_len (1024 blocks -> ~full HBM BW on the 536 MB qf read)
__global__ __launch_bounds__(256) void k_h0_part(const float4* __restrict__ qf4,
                                                 const float* __restrict__ w_in,
                                                 float4* __restrict__ part) {
    int b = blockIdx.x >> 2;
    int kq = blockIdx.x & 3;
    int hq = threadIdx.x;
    const float4* p = qf4 + (size_t)b * IN_LEN * 256 + (size_t)kq * 128 * 256 + hq;
    const float* wv = w_in + kq * 128;
    float4 s = make_float4(0.f, 0.f, 0.f, 0.f);
#pragma unroll 8
    for (int i = 0; i < 128; ++i) {
        float w = wv[i];
        float4 q = p[(size_t)i * 256];
        s.x += q.x * w; s.y += q.y * w; s.z += q.z * w; s.w += q.w * w;
    }
    part[((size_t)kq * 256 + b) * 256 + hq] = s;
}

// ---- combine partials, add b_in, split to bf16 hi/lo; zero the cell state
__global__ __launch_bounds__(256) void k_h0_comb(const float4* __restrict__ part,
                                                 const float* __restrict__ b_in,
                                                 ushort4* __restrict__ h0h, ushort4* __restrict__ h0l,
                                                 float4* __restrict__ c4) {
    int idx = blockIdx.x * 256 + threadIdx.x;   // b*256 + hq
    float4 s = part[idx];
    float4 s1 = part[65536 + idx];
    float4 s2 = part[131072 + idx];
    float4 s3 = part[196608 + idx];
    s.x += s1.x + s2.x + s3.x;
    s.y += s1.y + s2.y + s3.y;
    s.z += s1.z + s2.z + s3.z;
    s.w += s1.w + s2.w + s3.w;
    float bi = b_in[0];
    s.x += bi; s.y += bi; s.z += bi; s.w += bi;
    ushort4 hi, lo;
    hi.x = f2bf(s.x); lo.x = f2bf(s.x - bf2f(hi.x));
    hi.y = f2bf(s.y); lo.y = f2bf(s.y - bf2f(hi.y));
    hi.z = f2bf(s.z); lo.z = f2bf(s.z - bf2f(hi.z));
    hi.w = f2bf(s.w); lo.w = f2bf(s.w - bf2f(hi.w));
    h0h[idx] = hi;
    h0l[idx] = lo;
    c4[idx] = make_float4(0.f, 0.f, 0.f, 0.f);
}

// ---- one LSTM step: gates = h @ W^T (split-bf16 MFMA, 2-phase dbuf pipeline) + bias, then cell.
// grid (64,4): x = packed-col tile (64 cols), y = batch tile (64 rows). 512 threads = 8 waves.
// bid%8 = x%8 (64 % 8 == 0) -> each XCD sees 8 fixed col tiles (2 MB weights) across all 64
// launches -> weights stay L2-resident (no grid.sync, no L2 invalidation).
__global__ __launch_bounds__(512) void k_step(const ushort* __restrict__ Bh, const ushort* __restrict__ Bl,
                                              const float* __restrict__ bias,
                                              const ushort* __restrict__ Ah, const ushort* __restrict__ Al,
                                              int aStride,
                                              float* __restrict__ c,
                                              ushort* __restrict__ hsh, ushort* __restrict__ hsl,
                                              float* __restrict__ out_h, int t) {
    __shared__ __align__(16) ushort sA[2][2][64 * BK];   // [buf][hi/lo][64 rows x 64 k]
    __shared__ __align__(16) ushort sB[2][2][64 * BK];
    __shared__ __align__(16) float sC[64 * 68];

    const int tid = threadIdx.x;
    const int n0 = blockIdx.x * 64;     // packed col base (hh0 = n0/4)
    const int m0 = blockIdx.y * 64;     // batch base
    const int w = tid >> 6, l = tid & 63;
    const int wm = w & 1, wn = w >> 1;  // wave tile: 32 batch rows x 16 cols
    const int lm = l & 15, kg = l >> 4;

    // staging: each wave stages 8 rows (1 KB) per tensor-half per chunk via one gl_lds16.
    // LDS dest is linear (wave base + lane*16); swizzle achieved by permuting the global SOURCE slot.
    const int srow = (w << 3) + (l >> 3);              // tile row this lane stages
    const int sl8 = ((l & 7) ^ ((l >> 3) & 7)) * 8;    // swizzled source slot (elements)
    const int ldsW = w * 512;                          // wave's LDS dest (ushort offset)

    const ushort* pBh = Bh + (size_t)(n0 + srow) * H + sl8;
    const ushort* pBl = Bl + (size_t)(n0 + srow) * H + sl8;
    const ushort* pAh = Ah + (size_t)(m0 + srow) * aStride + sl8;
    const ushort* pAl = Al + (size_t)(m0 + srow) * aStride + sl8;

    const int ra0 = wm * 32 + lm;
    const int rb = wn * 16 + lm;

    f32x4 acc0 = (f32x4)(0.f), acc1 = (f32x4)(0.f);

    // prologue: stage chunk 0 -> buf 0
    gl_lds16(pAh, &sA[0][0][ldsW]);
    gl_lds16(pAl, &sA[0][1][ldsW]);
    gl_lds16(pBh, &sB[0][0][ldsW]);
    gl_lds16(pBl, &sB[0][1][ldsW]);
    __syncthreads();

#pragma unroll 2
    for (int ch = 0; ch < NCH; ++ch) {
        const int cur = ch & 1;
        if (ch + 1 < NCH) {                        // issue next chunk BEFORE compute (2-phase)
            const int k0 = (ch + 1) * BK;
            gl_lds16(pAh + k0, &sA[cur ^ 1][0][ldsW]);
            gl_lds16(pAl + k0, &sA[cur ^ 1][1][ldsW]);
            gl_lds16(pBh + k0, &sB[cur ^ 1][0][ldsW]);
            gl_lds16(pBl + k0, &sB[cur ^ 1][1][ldsW]);
        }
        const ushort* Ah_ = sA[cur][0];
        const ushort* Al_ = sA[cur][1];
        const ushort* Bh_ = sB[cur][0];
        const ushort* Bl_ = sB[cur][1];
#pragma unroll
        for (int ks = 0; ks < 2; ++ks) {
            const int ko = ks * 64 + kg * 16;      // byte offset within row
            bf16x8 a0h = FRAG(Ah_, ra0, ko);
            bf16x8 a0l = FRAG(Al_, ra0, ko);
            bf16x8 a1h = FRAG(Ah_, ra0 + 16, ko);
            bf16x8 a1l = FRAG(Al_, ra0 + 16, ko);
            bf16x8 bh_ = FRAG(Bh_, rb, ko);
            bf16x8 bl_ = FRAG(Bl_, rb, ko);
            acc0 = __builtin_amdgcn_mfma_f32_16x16x32_bf16(a0h, bh_, acc0, 0, 0, 0);
            acc0 = __builtin_amdgcn_mfma_f32_16x16x32_bf16(a0h, bl_, acc0, 0, 0, 0);
            acc0 = __builtin_amdgcn_mfma_f32_16x16x32_bf16(a0l, bh_, acc0, 0, 0, 0);
            acc1 = __builtin_amdgcn_mfma_f32_16x16x32_bf16(a1h, bh_, acc1, 0, 0, 0);
            acc1 = __builtin_amdgcn_mfma_f32_16x16x32_bf16(a1h, bl_, acc1, 0, 0, 0);
            acc1 = __builtin_amdgcn_mfma_f32_16x16x32_bf16(a1l, bh_, acc1, 0, 0, 0);
        }
        __syncthreads();   // drains this chunk's prefetch; protects buf reuse
    }

    // spill C tile (rows = batch, cols = packed col)
    {
        const int c0 = wn * 16 + lm;
        const int r0 = wm * 32 + kg * 4;
#pragma unroll
        for (int r = 0; r < 4; ++r) sC[(r0 + r) * 68 + c0] = acc0[r];
#pragma unroll
        for (int r = 0; r < 4; ++r) sC[(r0 + 16 + r) * 68 + c0] = acc1[r];
    }
    __syncthreads();

    // cell update: 2 cells/thread; c round-trips through global (L2-resident, 1 MB)
#pragma unroll
    for (int q = 0; q < 2; ++q) {
        int cid = tid + q * 512;
        int bl_ = cid >> 4, hl = cid & 15;
        float4 gv = *(const float4*)&sC[bl_ * 68 + hl * 4];   // i,f,g,o
        float4 bv = *(const float4*)&bias[n0 + hl * 4];
        int b = m0 + bl_;
        int hh = (n0 >> 2) + hl;
        float cold = c[b * H + hh];
        float ig = gv.x + bv.x, fg = gv.y + bv.y, gg = gv.z + bv.z, og = gv.w + bv.w;
        float cn = sigf(fg) * cold + sigf(ig) * tanhfast(gg);
        float hn = sigf(og) * tanhfast(cn);
        c[b * H + hh] = cn;
        size_t idx = ((size_t)b * T_OUT + t) * H + hh;
        out_h[idx] = hn;
        unsigned short hb = f2bf(hn);
        hsh[idx] = hb;
        hsl[idx] = f2bf(hn - bf2f(hb));
    }
}

// ---- probs = hs @ w_out^T + b_out (split-bf16 MFMA, same staging engine)
// grid 256: block bid covers hs rows [bid*64, bid*64+64) = batch bid, all t.
__global__ __launch_bounds__(512) void k_probs(const ushort* __restrict__ hsh, const ushort* __restrict__ hsl,
                                               const ushort* __restrict__ woh, const ushort* __restrict__ wol,
                                               const float* __restrict__ b_out,
                                               float* __restrict__ probs) {
    __shared__ __align__(16) ushort sA[2][2][64 * BK];
    __shared__ __align__(16) ushort sB[2][2][64 * BK];

    const int tid = threadIdx.x;
    const int bid = blockIdx.x;
    const int w = tid >> 6, l = tid & 63;
    const int wm = w & 1, wn = w >> 1;
    const int lm = l & 15, kg = l >> 4;

    const int srow = (w << 3) + (l >> 3);
    const int sl8 = ((l & 7) ^ ((l >> 3) & 7)) * 8;
    const int ldsW = w * 512;

    const ushort* pAh = hsh + (size_t)(bid * 64 + srow) * H + sl8;
    const ushort* pAl = hsl + (size_t)(bid * 64 + srow) * H + sl8;
    const ushort* pBh = woh + (size_t)srow * H + sl8;
    const ushort* pBl = wol + (size_t)srow * H + sl8;

    const int ra0 = wm * 32 + lm;
    const int rb = wn * 16 + lm;

    f32x4 acc0 = (f32x4)(0.f), acc1 = (f32x4)(0.f);

    gl_lds16(pAh, &sA[0][0][ldsW]);
    gl_lds16(pAl, &sA[0][1][ldsW]);
    gl_lds16(pBh, &sB[0][0][ldsW]);
    gl_lds16(pBl, &sB[0][1][ldsW]);
    __syncthreads();

#pragma unroll 2
    for (int ch = 0; ch < NCH; ++ch) {
        const int cur = ch & 1;
        if (ch + 1 < NCH) {
            const int k0 = (ch + 1) * BK;
            gl_lds16(pAh + k0, &sA[cur ^ 1][0][ldsW]);
            gl_lds16(pAl + k0, &sA[cur ^ 1][1][ldsW]);
            gl_lds16(pBh + k0, &sB[cur ^ 1][0][ldsW]);
            gl_lds16(pBl + k0, &sB[cur ^ 1][1][ldsW]);
        }
        const ushort* Ah_ = sA[cur][0];
        const ushort* Al_ = sA[cur][1];
        const ushort* Bh_ = sB[cur][0];
        const ushort* Bl_ = sB[cur][1];
#pragma unroll
        for (int ks = 0; ks < 2; ++ks) {
            const int ko = ks * 64 + kg * 16;
            bf16x8 a0h = FRAG(Ah_, ra0, ko);
            bf16x8 a0l = FRAG(Al_, ra0, ko);
            bf16x8 a1h = FRAG(Ah_, ra0 + 16, ko);
            bf16x8 a1l = FRAG(Al_, ra0 + 16, ko);
            bf16x8 bh_ = FRAG(Bh_, rb, ko);
            bf16x8 bl_ = FRAG(Bl_, rb, ko);
            acc0 = __builtin_amdgcn_mfma_f32_16x16x32_bf16(a0h, bh_, acc0, 0, 0, 0);
            acc0 = __builtin_amdgcn_mfma_f32_16x16x32_bf16(a0h, bl_, acc0, 0, 0, 0);
            acc0 = __builtin_amdgcn_mfma_f32_16x16x32_bf16(a0l, bh_, acc0, 0, 0, 0);
            acc1 = __builtin_amdgcn_mfma_f32_16x16x32_bf16(a1h, bh_, acc1, 0, 0, 0);
            acc1 = __builtin_amdgcn_mfma_f32_16x16x32_bf16(a1h, bl_, acc1, 0, 0, 0);
            acc1 = __builtin_amdgcn_mfma_f32_16x16x32_bf16(a1l, bh_, acc1, 0, 0, 0);
        }
        __syncthreads();
    }

    const int col = wn * 16 + lm;
    const float bo = b_out[col];
    const int rowb = bid * 64 + wm * 32 + kg * 4;
#pragma unroll
    for (int r = 0; r < 4; ++r)
        probs[(size_t)(rowb + r) * 64 + col] = acc0[r] + bo;
#pragma unroll
    for (int r = 0; r < 4; ++r)
        probs[(size_t)(rowb + 16 + r) * 64 + col] = acc1[r] + bo;
}

extern "C" void kernel_launch(void* const* d_in, const int* in_sizes, int n_in,
                              void* d_out, int out_size, void* d_ws, size_t ws_size,
                              hipStream_t stream) {
    const float* qf    = (const float*)d_in[1];
    const float* st    = (const float*)d_in[4];
    const float* w_in  = (const float*)d_in[5];
    const float* b_in  = (const float*)d_in[6];
    const float* w_ih  = (const float*)d_in[7];
    const float* w_hh  = (const float*)d_in[8];
    const float* b_ih  = (const float*)d_in[9];
    const float* b_hh  = (const float*)d_in[10];
    const float* w_out = (const float*)d_in[11];
    const float* b_out = (const float*)d_in[12];

    float* probs = (float*)d_out;                        // [256][64][64]
    float* out_h = probs + (size_t)BS * T_OUT * 64;      // [256][64][1024]

    char* ws = (char*)d_ws;
    ushort* Wch   = (ushort*)ws; ws += (size_t)G4 * H * 2;         // 8 MB
    ushort* Wcl   = (ushort*)ws; ws += (size_t)G4 * H * 2;         // 8 MB
    ushort* Whh_h = (ushort*)ws; ws += (size_t)G4 * H * 2;         // 8 MB
    ushort* Whh_l = (ushort*)ws; ws += (size_t)G4 * H * 2;         // 8 MB
    ushort* woh   = (ushort*)ws; ws += (size_t)64 * H * 2;
    ushort* wol   = (ushort*)ws; ws += (size_t)64 * H * 2;
    float*  bcp   = (float*)ws;  ws += G4 * 4;
    float*  g0p   = (float*)ws;  ws += G4 * 4;
    ushort* h0h   = (ushort*)ws; ws += (size_t)BS * H * 2;         // 512 KB
    ushort* h0l   = (ushort*)ws; ws += (size_t)BS * H * 2;
    ushort* hsh   = (ushort*)ws; ws += (size_t)BS * T_OUT * H * 2; // 32 MB
    ushort* hsl   = (ushort*)ws; ws += (size_t)BS * T_OUT * H * 2; // 32 MB
    float*  cb    = (float*)ws;  ws += (size_t)BS * H * 4;         // 1 MB
    float*  part  = (float*)ws;  ws += (size_t)4 * 256 * 256 * 16; // 4 MB

    k_prep<<<G4, 256, 0, stream>>>((const float4*)w_ih, (const float4*)w_hh, (const float4*)w_out,
                                   (ushort4*)Wch, (ushort4*)Wcl, (ushort4*)Whh_h, (ushort4*)Whh_l,
                                   (ushort4*)woh, (ushort4*)wol);
    k_g0<<<G4 / 4, 256, 0, stream>>>((const float4*)st, (const float4*)w_ih, b_ih, b_hh, g0p, bcp);
    k_h0_part<<<BS * 4, 256, 0, stream>>>((const float4*)qf, w_in, (float4*)part);
    k_h0_comb<<<BS, 256, 0, stream>>>((const float4*)part, b_in, (ushort4*)h0h, (ushort4*)h0l,
                                      (float4*)cb);

    for (int t = 0; t < T_OUT; ++t) {
        const ushort* Bh = (t == 0) ? Whh_h : Wch;
        const ushort* Bl = (t == 0) ? Whh_l : Wcl;
        const float* bias = (t == 0) ? g0p : bcp;
        const ushort* Ah = (t == 0) ? h0h : (hsh + (size_t)(t - 1) * H);
        const ushort* Al = (t == 0) ? h0l : (hsl + (size_t)(t - 1) * H);
        int aStride = (t == 0) ? H : (T_OUT * H);
        k_step<<<dim3(64, 4), 512, 0, stream>>>(Bh, Bl, bias, Ah, Al, aStride,
                                                cb, hsh, hsl, out_h, t);
    }
    k_probs<<<BS * T_OUT / 64, 512, 0, stream>>>(hsh, hsl, woh, wol, b_out, probs);
}